// Round 10
// baseline (54.836 us; speedup 1.0000x reference)
//
#include <hip/hip_runtime.h>
#include <math.h>

#define T_LEN 1024
#define PRED_LEN 256
#define OUT_T (T_LEN + PRED_LEN)
#define DM 256
#define KSEL 32

#define TWO_PI_F 6.2831853071795864769f
#define INV1024  0.0009765625f
#define RTAU 1e-4f

// pad every 32 floats by 1 to break power-of-2 bank strides
#define SPAD(i) ((i) + ((i) >> 5))

// W16[e] = exp(-2*pi*i*e/16), fp32
__device__ __constant__ float W16RF[16] = {
    1.0f,  0.92387953f,  0.70710678f,  0.38268343f, 0.0f, -0.38268343f, -0.70710678f, -0.92387953f,
   -1.0f, -0.92387953f, -0.70710678f, -0.38268343f, 0.0f,  0.38268343f,  0.70710678f,  0.92387953f };
__device__ __constant__ float W16IF[16] = {
    0.0f, -0.38268343f, -0.70710678f, -0.92387953f, -1.0f, -0.92387953f, -0.70710678f, -0.38268343f,
    0.0f,  0.38268343f,  0.70710678f,  0.92387953f,  1.0f,  0.92387953f,  0.70710678f,  0.38268343f };

// ---------------- Kernel T: twiddle tables W[e] = exp(-2pi*i*e/1024), fp64 + fp32 ----------------
__global__ void fl_twiddle_kernel(double* __restrict__ gwr, double* __restrict__ gwi,
                                  float* __restrict__ gwrF, float* __restrict__ gwiF) {
    int e = blockIdx.x * 64 + threadIdx.x;
    double ang = (double)e * (6.283185307179586476925286766559 / 1024.0);
    double c = cos(ang), s = -sin(ang);
    gwr[e] = c; gwi[e] = s;
    gwrF[e] = (float)c; gwiF[e] = (float)s;
}

// ---------------- Fused: fp32 packed FFT + hist top-32 + fp64 boundary refine + synthesis ----------------
// grid = 2048 blocks: TWO blocks per column-pair (each synthesizes half the j-range).
// block = 256 threads = 4 waves; 8 blocks/CU co-resident (LDS ~17.4 KB, VGPR <= 64).
__global__ void __launch_bounds__(256, 8)
fl_fused_kernel(const float* __restrict__ x,
                const double* __restrict__ gwr, const double* __restrict__ gwi,
                const float* __restrict__ gwrF, const float* __restrict__ gwiF,
                float* __restrict__ out) {
    __shared__ float gspR[SPAD(1023) + 1], gspI[SPAD(1023) + 1];  // fp32 twiddles, then spectrum
    __shared__ char smemU[8192];     // union: xsh (FFT input) | {mg, hist}
    __shared__ int   selMs[2 * KSEL];
    __shared__ float selAs[2 * KSEL], selBs[2 * KSEL];
    float2* xsh  = (float2*)smemU;
    float*  mg   = (float*)smemU;                 // [1024] |X|^2 both columns
    int*    hist = (int*)(smemU + 4096);          // [512]

    const int tid  = threadIdx.x;
    const int lane = tid & 63;       // = n2
    const int w    = tid >> 6;       // wave 0..3

    // block mapping: xcd-colocated pair-halves. b = xcd, lp = local pair, p = j-half.
    const int bid = blockIdx.x;
    const int b   = bid & 7;                 // batch == XCD (heuristic only)
    const int t_  = bid >> 3;                // 0..255
    const int p   = t_ & 1;                  // synth j-half
    const int lp  = t_ >> 1;                 // 0..127
    const int d0  = lp << 1;

    // stage fp32 twiddles (padded) and the packed column-pair into LDS
    for (int j = 0; j < 4; ++j) {
        int e = tid + (j << 8);
        gspR[SPAD(e)] = gwrF[e];
        gspI[SPAD(e)] = gwiF[e];
        xsh[e] = *reinterpret_cast<const float2*>(&x[(((size_t)(b << 10) + e) << 8) + d0]);
    }
    __syncthreads();

    // ---- FFT-16 over n1 (fp32): shared DFT-4 partials, then 4 outputs k1 = 4w+q
    float Fr[4][4], Fi[4][4];
#pragma unroll
    for (int n1a = 0; n1a < 4; ++n1a) {
        float2 a  = xsh[lane + 64 * (n1a + 0)];
        float2 bb = xsh[lane + 64 * (n1a + 4)];
        float2 cV = xsh[lane + 64 * (n1a + 8)];
        float2 d  = xsh[lane + 64 * (n1a + 12)];
        float t0r = a.x + cV.x, t0i = a.y + cV.y;
        float t1r = a.x - cV.x, t1i = a.y - cV.y;
        float t2r = bb.x + d.x, t2i = bb.y + d.y;
        float t3r = bb.x - d.x, t3i = bb.y - d.y;
        Fr[n1a][0] = t0r + t2r;  Fi[n1a][0] = t0i + t2i;
        Fr[n1a][2] = t0r - t2r;  Fi[n1a][2] = t0i - t2i;
        Fr[n1a][1] = t1r + t3i;  Fi[n1a][1] = t1i - t3r;   // t1 - i*t3
        Fr[n1a][3] = t1r - t3i;  Fi[n1a][3] = t1i + t3r;   // t1 + i*t3
    }

    float ar[4], ai[4];
#pragma unroll
    for (int q = 0; q < 4; ++q) {
        const int k1 = (w << 2) | q;
        float cr = Fr[0][q], ci = Fi[0][q];
#pragma unroll
        for (int n1a = 1; n1a < 4; ++n1a) {
            int e = (n1a * k1) & 15;
            float wr = W16RF[e], wi = W16IF[e];
            cr += Fr[n1a][q] * wr - Fi[n1a][q] * wi;
            ci += Fr[n1a][q] * wi + Fi[n1a][q] * wr;
        }
        int et = (lane * k1) & 1023;
        float twr = gspR[SPAD(et)], twi = gspI[SPAD(et)];
        ar[q] = cr * twr - ci * twi;
        ai[q] = cr * twi + ci * twr;
    }

    // ---- FFT-64 over n2, cross-lane DIF (fp32 shfl), 4 independent chains
#pragma unroll
    for (int s = 0; s < 6; ++s) {
        const int half = 32 >> s;
        const int e = (lane & (half - 1)) << s;
        const float wr = gspR[SPAD(e << 4)];   // W64^e = W1024^(16e)
        const float wi = gspI[SPAD(e << 4)];
        const bool up = (lane & half) != 0;
#pragma unroll
        for (int q = 0; q < 4; ++q) {
            float orr = __shfl_xor(ar[q], half);
            float oii = __shfl_xor(ai[q], half);
            float sr = ar[q] + orr, si = ai[q] + oii;
            float dr = orr - ar[q], di = oii - ai[q];
            float ur = dr * wr - di * wi;
            float ui = dr * wi + di * wr;
            ar[q] = up ? ur : sr;
            ai[q] = up ? ui : si;
        }
    }
    __syncthreads();   // all twiddle-table reads done; gspR/gspI becomes the spectrum

    {
        const int krev = (int)(__brev((unsigned)lane) >> 26);  // rev6(lane) = k2
#pragma unroll
        for (int q = 0; q < 4; ++q) {
            int k = ((w << 2) | q) + (krev << 4);              // X[k1 + 16*k2]
            gspR[SPAD(k)] = ar[q];
            gspI[SPAD(k)] = ai[q];
        }
    }
    __syncthreads();

    // ---- magnitudes for both packed columns (conjugate-symmetry unpack); overwrites xsh
#pragma unroll
    for (int h = 0; h < 2; ++h) {
        int m = tid + (h << 8);
        int n = (1024 - m) & 1023;
        float rm = gspR[SPAD(m)], iv = gspI[SPAD(m)];
        float rn = gspR[SPAD(n)], in_ = gspI[SPAD(n)];
        float rr0 = 0.5f * (rm + rn),  ii0 = 0.5f * (iv - in_);
        float rr1 = 0.5f * (iv + in_), ii1 = 0.5f * (rn - rm);
        mg[m]       = rr0 * rr0 + ii0 * ii0;
        mg[512 + m] = rr1 * rr1 + ii1 * ii1;
    }
    __syncthreads();

    // ---- histogram top-32 (waves 0,1: one wave per column) + fp64 boundary refinement
    if (tid < 128) {
        const int c = tid >> 6;
        const float* mgc = mg + (c << 9);
        int* histc = hist + (c << 8);

        float v[8]; int hiw[8];
#pragma unroll
        for (int q = 0; q < 8; ++q) v[q] = mgc[(q << 6) | lane];
        if (lane == 0) v[0] = -1.0f;   // exclude m=0; m=512 excluded by range
#pragma unroll
        for (int q = 0; q < 8; ++q) hiw[q] = __float_as_int(v[q]);

        int mx = hiw[0];
#pragma unroll
        for (int q = 1; q < 8; ++q) mx = max(mx, hiw[q]);
#pragma unroll
        for (int off = 1; off < 64; off <<= 1) mx = max(mx, __shfl_xor(mx, off));

        const int base = (mx >> 20) - 250;
        int idx[8];
#pragma unroll
        for (int q = 0; q < 8; ++q) {
            int t = (hiw[q] >> 20) - base;
            idx[q] = t < 0 ? 0 : t;
        }

        *reinterpret_cast<int4*>(&histc[lane << 2]) = int4{0, 0, 0, 0};
#pragma unroll
        for (int q = 0; q < 8; ++q) atomicAdd(&histc[idx[q]], 1);

        int4 cc = *reinterpret_cast<int4*>(&histc[lane << 2]);
        int s_local = cc.x + cc.y + cc.z + cc.w;

        int s = s_local;
#pragma unroll
        for (int off = 1; off < 64; off <<= 1) {
            int t = __shfl_down(s, off);
            if (lane + off < 64) s += t;
        }
        const int S_gt = s - s_local;
        const int A3 = S_gt;
        const int A2 = A3 + cc.w;
        const int A1 = A2 + cc.z;
        const int A0 = A1 + cc.y;

        int foundB = -1, foundR = 0;
        if (A0 < KSEL && A0 + cc.x >= KSEL) { foundB = (lane << 2) | 0; foundR = KSEL - A0; }
        if (A1 < KSEL && A1 + cc.y >= KSEL) { foundB = (lane << 2) | 1; foundR = KSEL - A1; }
        if (A2 < KSEL && A2 + cc.z >= KSEL) { foundB = (lane << 2) | 2; foundR = KSEL - A2; }
        if (A3 < KSEL && A3 + cc.w >= KSEL) { foundB = (lane << 2) | 3; foundR = KSEL - A3; }

        unsigned long long fm = __ballot(foundB >= 0);
        const int srcB = (int)(__ffsll((unsigned long long)fm) - 1);
        const int B = __shfl(foundB, srcB);
        const int r = __shfl(foundR, srcB);

        unsigned selmask = 0, candmask = 0;
#pragma unroll
        for (int q = 0; q < 8; ++q) {
            if (idx[q] > B) selmask |= (1u << q);
            else if (idx[q] == B) candmask |= (1u << q);
        }

        for (int it = 0; it < r; ++it) {
            float bv = -2.0f; int bq = -1;
#pragma unroll
            for (int q = 0; q < 8; ++q) {
                bool cand = ((candmask >> q) & 1u) != 0;
                if (cand && v[q] > bv) { bv = v[q]; bq = q; }
            }
            int bi = (bq < 0) ? 0x7FFFFFFF : ((bq << 6) | lane);
#pragma unroll
            for (int off = 1; off < 64; off <<= 1) {
                float ov = __shfl_xor(bv, off);
                int   oi = __shfl_xor(bi, off);
                if (ov > bv || (ov == bv && oi < bi)) { bv = ov; bi = oi; }
            }
            if (bi != 0x7FFFFFFF && lane == (bi & 63)) {
                unsigned bit = 1u << (bi >> 6);
                selmask  |= bit;
                candmask &= ~bit;
            }
        }

        // ---- fp64 refinement when the rank-32/33 fp32 gap is too small (reads x from global)
        {
            float vminS = 3.0e38f, vmaxU = -3.0e38f;
#pragma unroll
            for (int q = 0; q < 8; ++q) {
                if ((selmask >> q) & 1u) vminS = fminf(vminS, v[q]);
                else                     vmaxU = fmaxf(vmaxU, v[q]);
            }
#pragma unroll
            for (int off = 1; off < 64; off <<= 1) {
                vminS = fminf(vminS, __shfl_xor(vminS, off));
                vmaxU = fmaxf(vmaxU, __shfl_xor(vmaxU, off));
            }
            const float tau = RTAU * vminS;
            if (vminS - vmaxU < tau) {            // wave-uniform, rare
                const float lo = vmaxU - tau, hi = vminS + tau;
                unsigned candq = 0; int nAbove = 0;
#pragma unroll
                for (int q = 0; q < 8; ++q) {
                    bool inw = (v[q] >= lo) && (v[q] <= hi);
                    if (inw) candq |= (1u << q);
                    if (((selmask >> q) & 1u) && v[q] > hi) ++nAbove;
                }
#pragma unroll
                for (int off = 1; off < 64; off <<= 1) nAbove += __shfl_xor(nAbove, off);
                const int kneed = KSEL - nAbove;
                selmask &= ~candq;                 // drop window members; re-pick in fp64

                const float* xcol = x + ((size_t)(b << 10) << 8) + d0 + c;
                double sV = -1.0; int sSrc = 0; int cnum = 0;
                for (int q = 0; q < 8; ++q) {
                    unsigned long long bal = __ballot((candq >> q) & 1u);
                    while (bal) {
                        int srcl = (int)(__ffsll(bal) - 1);
                        bal &= bal - 1;
                        int m = (q << 6) | srcl;
                        double sr = 0.0, si = 0.0;
                        for (int u = 0; u < 16; ++u) {
                            int n = lane + (u << 6);
                            double xvd = (double)xcol[(size_t)n << 8];
                            int e = (m * n) & 1023;
                            sr = fma(xvd, gwr[e], sr);
                            si = fma(xvd, gwi[e], si);
                        }
#pragma unroll
                        for (int off = 1; off < 64; off <<= 1) {
                            sr += __shfl_xor(sr, off);
                            si += __shfl_xor(si, off);
                        }
                        if (lane == cnum) { sV = sr * sr + si * si; sSrc = (q << 6) | srcl; }
                        ++cnum;
                        if (cnum >= 64) break;
                    }
                    if (cnum >= 64) break;
                }
                for (int it = 0; it < kneed; ++it) {
                    double bv = sV; int bl = lane;
#pragma unroll
                    for (int off = 1; off < 64; off <<= 1) {
                        double ov = __shfl_xor(bv, off);
                        int    ol = __shfl_xor(bl, off);
                        if (ov > bv || (ov == bv && ol < bl)) { bv = ov; bl = ol; }
                    }
                    int wsrc = __shfl(sSrc, bl);
                    if (lane == (wsrc & 63)) selmask |= 1u << (wsrc >> 6);
                    if (lane == bl) sV = -2.0;
                }
            }
        }

        const int cnt = __popc(selmask);
        int pp = cnt;
#pragma unroll
        for (int off = 1; off < 64; off <<= 1) {
            int t = __shfl_up(pp, off);
            if (lane >= off) pp += t;
        }
        int slot = (c << 5) + (pp - cnt);

#pragma unroll
        for (int q = 0; q < 8; ++q) {
            if ((selmask >> q) & 1u) {
                int m = (q << 6) | lane;
                int n = (1024 - m) & 1023;
                float rm = gspR[SPAD(m)], iv = gspI[SPAD(m)];
                float rn = gspR[SPAD(n)], in_ = gspI[SPAD(n)];
                float rr, ii;
                if (c == 0) { rr = 0.5f * (rm + rn);  ii = 0.5f * (iv - in_); }
                else        { rr = 0.5f * (iv + in_); ii = 0.5f * (rn - rm); }
                selMs[slot] = m;
                selAs[slot] = rr * (1.0f / 512.0f);      //  2*Re/T
                selBs[slot] = -ii * (1.0f / 512.0f);     // -2*Im/T
                ++slot;
            }
        }
    }
    __syncthreads();

    // ---- synthesis: wave-uniform column; tv = j + 256*i; this block does j-half p
    {
        const int col = w & 1;
        const int jl  = ((w >> 1) << 6) | lane;   // 0..127
        const int j   = (p << 7) | jl;            // 0..255
        float a0 = 0.f, a1 = 0.f, a2 = 0.f, a3 = 0.f, a4 = 0.f;
        const int cbase = col << 5;
        for (int k = 0; k < KSEL; ++k) {
            const int   m = selMs[cbase + k];
            const float A = selAs[cbase + k];
            const float B = selBs[cbase + k];
            const float th = (float)((m * j) & 1023) * (INV1024 * TWO_PI_F);
            const float cs = __cosf(th);
            const float sn = __sinf(th);
            const float c0 = fmaf(A, cs, B * sn);
            // phase step per i is (pi/2)*(m&3): exact +/-/swap
            switch (m & 3) {
                case 0: a0 += c0; a1 += c0; a2 += c0; a3 += c0; a4 += c0; break;
                case 2: a0 += c0; a1 -= c0; a2 += c0; a3 -= c0; a4 += c0; break;
                case 1: { float c1 = fmaf(B, cs, -(A * sn));
                          a0 += c0; a1 += c1; a2 -= c0; a3 -= c1; a4 += c0; } break;
                default:{ float c1 = fmaf(B, cs, -(A * sn));
                          a0 += c0; a1 -= c1; a2 -= c0; a3 += c1; a4 += c0; } break;
            }
        }
        float* op = out + ((size_t)b * OUT_T + j) * DM + d0 + col;
        op[0]                   = a0;
        op[(size_t)256  * DM]   = a1;
        op[(size_t)512  * DM]   = a2;
        op[(size_t)768  * DM]   = a3;
        op[(size_t)1024 * DM]   = a4;
    }
}

extern "C" void kernel_launch(void* const* d_in, const int* in_sizes, int n_in,
                              void* d_out, int out_size, void* d_ws, size_t ws_size,
                              hipStream_t stream) {
    const float* x = (const float*)d_in[0];
    float* out = (float*)d_out;

    char* w = (char*)d_ws;
    double* gwr  = (double*)(w);
    double* gwi  = (double*)(w + 1024 * sizeof(double));
    float*  gwrF = (float*)(w + 2048 * sizeof(double));
    float*  gwiF = (float*)(w + 2048 * sizeof(double) + 1024 * sizeof(float));

    hipLaunchKernelGGL(fl_twiddle_kernel, dim3(16), dim3(64), 0, stream, gwr, gwi, gwrF, gwiF);
    hipLaunchKernelGGL(fl_fused_kernel, dim3(2048), dim3(256), 0, stream,
                       x, gwr, gwi, gwrF, gwiF, out);
}

// Round 11
// 47.894 us; speedup vs baseline: 1.1449x; 1.1449x over previous
//
#include <hip/hip_runtime.h>
#include <math.h>

#define T_LEN 1024
#define PRED_LEN 256
#define OUT_T (T_LEN + PRED_LEN)
#define DM 256
#define KSEL 32

#define TWO_PI_F 6.2831853071795864769f
#define INV1024  0.0009765625f
#define RTAU 1e-4f

// pad every 32 floats by 1 to break power-of-2 bank strides
#define SPAD(i) ((i) + ((i) >> 5))

// W16[e] = exp(-2*pi*i*e/16), fp32
__device__ __constant__ float W16RF[16] = {
    1.0f,  0.92387953f,  0.70710678f,  0.38268343f, 0.0f, -0.38268343f, -0.70710678f, -0.92387953f,
   -1.0f, -0.92387953f, -0.70710678f, -0.38268343f, 0.0f,  0.38268343f,  0.70710678f,  0.92387953f };
__device__ __constant__ float W16IF[16] = {
    0.0f, -0.38268343f, -0.70710678f, -0.92387953f, -1.0f, -0.92387953f, -0.70710678f, -0.38268343f,
    0.0f,  0.38268343f,  0.70710678f,  0.92387953f,  1.0f,  0.92387953f,  0.70710678f,  0.38268343f };

// ---------------- Kernel T: twiddle tables W[e] = exp(-2pi*i*e/1024), fp64 + fp32 ----------------
__global__ void fl_twiddle_kernel(double* __restrict__ gwr, double* __restrict__ gwi,
                                  float* __restrict__ gwrF, float* __restrict__ gwiF) {
    int e = blockIdx.x * 64 + threadIdx.x;
    double ang = (double)e * (6.283185307179586476925286766559 / 1024.0);
    double c = cos(ang), s = -sin(ang);
    gwr[e] = c; gwi[e] = s;
    gwrF[e] = (float)c; gwiF[e] = (float)s;
}

// ---------------- Fused: fp32 packed FFT + hist top-32 + fp64 boundary refine + synthesis ----------------
// grid = 1024 blocks (ONE block per column-pair, no duplication), block = 512 threads = 8 waves.
// 4 blocks/CU co-resident -> 32 waves/CU (full). VGPR capped 64 by launch_bounds(512,8).
__global__ void __launch_bounds__(512, 8)
fl_fused_kernel(const float* __restrict__ x,
                const double* __restrict__ gwr, const double* __restrict__ gwi,
                const float* __restrict__ gwrF, const float* __restrict__ gwiF,
                float* __restrict__ out) {
    __shared__ float gspR[SPAD(1023) + 1], gspI[SPAD(1023) + 1];  // fp32 twiddles, then spectrum
    __shared__ char smemU[8192];     // union: xsh (FFT input) | {mg, hist}
    __shared__ int   selMs[2 * KSEL];
    __shared__ float selAs[2 * KSEL], selBs[2 * KSEL];
    float2* xsh  = (float2*)smemU;
    float*  mg   = (float*)smemU;                 // [1024] |X|^2 both columns
    int*    hist = (int*)(smemU + 4096);          // [512]

    const int tid  = threadIdx.x;
    const int lane = tid & 63;       // = n2
    const int w    = tid >> 6;       // wave 0..7

    const int bid = blockIdx.x;
    const int sp  = ((bid & 7) << 7) | (bid >> 3);   // XCD-chunked, bijective over 1024
    const int b   = sp >> 7;
    const int d0  = (sp & 127) << 1;

    // stage fp32 twiddles (padded) and the packed column-pair into LDS (2 each)
    for (int j = 0; j < 2; ++j) {
        int e = tid + (j << 9);
        gspR[SPAD(e)] = gwrF[e];
        gspI[SPAD(e)] = gwiF[e];
        xsh[e] = *reinterpret_cast<const float2*>(&x[(((size_t)(b << 10) + e) << 8) + d0]);
    }
    __syncthreads();

    // ---- FFT-16 over n1 (fp32): each wave owns k1 = 2w+q (q=0,1); f = k1&3 in {f0, f0+1}
    const int f0 = (w << 1) & 3;     // wave-uniform: 0 or 2
    float Fr[4][2], Fi[4][2];
#pragma unroll
    for (int n1a = 0; n1a < 4; ++n1a) {
        float2 a  = xsh[lane + 64 * (n1a + 0)];
        float2 bb = xsh[lane + 64 * (n1a + 4)];
        float2 cV = xsh[lane + 64 * (n1a + 8)];
        float2 d  = xsh[lane + 64 * (n1a + 12)];
        float t0r = a.x + cV.x, t0i = a.y + cV.y;
        float t1r = a.x - cV.x, t1i = a.y - cV.y;
        float t2r = bb.x + d.x, t2i = bb.y + d.y;
        float t3r = bb.x - d.x, t3i = bb.y - d.y;
        if (f0 == 0) {
            Fr[n1a][0] = t0r + t2r;  Fi[n1a][0] = t0i + t2i;     // f=0
            Fr[n1a][1] = t1r + t3i;  Fi[n1a][1] = t1i - t3r;     // f=1: t1 - i*t3
        } else {
            Fr[n1a][0] = t0r - t2r;  Fi[n1a][0] = t0i - t2i;     // f=2
            Fr[n1a][1] = t1r - t3i;  Fi[n1a][1] = t1i + t3r;     // f=3: t1 + i*t3
        }
    }

    float ar[2], ai[2];
#pragma unroll
    for (int q = 0; q < 2; ++q) {
        const int k1 = (w << 1) | q;
        float cr = Fr[0][q], ci = Fi[0][q];
#pragma unroll
        for (int n1a = 1; n1a < 4; ++n1a) {
            int e = (n1a * k1) & 15;
            float wr = W16RF[e], wi = W16IF[e];
            cr += Fr[n1a][q] * wr - Fi[n1a][q] * wi;
            ci += Fr[n1a][q] * wi + Fi[n1a][q] * wr;
        }
        int et = (lane * k1) & 1023;
        float twr = gspR[SPAD(et)], twi = gspI[SPAD(et)];
        ar[q] = cr * twr - ci * twi;
        ai[q] = cr * twi + ci * twr;
    }

    // ---- FFT-64 over n2, cross-lane DIF (fp32 shfl), 2 independent chains
#pragma unroll
    for (int s = 0; s < 6; ++s) {
        const int half = 32 >> s;
        const int e = (lane & (half - 1)) << s;
        const float wr = gspR[SPAD(e << 4)];   // W64^e = W1024^(16e)
        const float wi = gspI[SPAD(e << 4)];
        const bool up = (lane & half) != 0;
#pragma unroll
        for (int q = 0; q < 2; ++q) {
            float orr = __shfl_xor(ar[q], half);
            float oii = __shfl_xor(ai[q], half);
            float sr = ar[q] + orr, si = ai[q] + oii;
            float dr = orr - ar[q], di = oii - ai[q];
            float ur = dr * wr - di * wi;
            float ui = dr * wi + di * wr;
            ar[q] = up ? ur : sr;
            ai[q] = up ? ui : si;
        }
    }
    __syncthreads();   // all twiddle-table reads done; gspR/gspI becomes the spectrum

    {
        const int krev = (int)(__brev((unsigned)lane) >> 26);  // rev6(lane) = k2
#pragma unroll
        for (int q = 0; q < 2; ++q) {
            int k = ((w << 1) | q) + (krev << 4);              // X[k1 + 16*k2]
            gspR[SPAD(k)] = ar[q];
            gspI[SPAD(k)] = ai[q];
        }
    }
    __syncthreads();

    // ---- magnitudes for both packed columns (conjugate-symmetry unpack); overwrites xsh
    {
        int m = tid & 511;             // 512 threads cover m = 0..511 once
        if (tid < 512) {
            int n = (1024 - m) & 1023;
            float rm = gspR[SPAD(m)], iv = gspI[SPAD(m)];
            float rn = gspR[SPAD(n)], in_ = gspI[SPAD(n)];
            float rr0 = 0.5f * (rm + rn),  ii0 = 0.5f * (iv - in_);
            float rr1 = 0.5f * (iv + in_), ii1 = 0.5f * (rn - rm);
            mg[m]       = rr0 * rr0 + ii0 * ii0;
            mg[512 + m] = rr1 * rr1 + ii1 * ii1;
        }
    }
    __syncthreads();

    // ---- histogram top-32 (waves 0,1: one wave per column) + fp64 boundary refinement
    if (tid < 128) {
        const int c = tid >> 6;
        const float* mgc = mg + (c << 9);
        int* histc = hist + (c << 8);

        float v[8]; int hiw[8];
#pragma unroll
        for (int q = 0; q < 8; ++q) v[q] = mgc[(q << 6) | lane];
        if (lane == 0) v[0] = -1.0f;   // exclude m=0; m=512 excluded by range
#pragma unroll
        for (int q = 0; q < 8; ++q) hiw[q] = __float_as_int(v[q]);

        int mx = hiw[0];
#pragma unroll
        for (int q = 1; q < 8; ++q) mx = max(mx, hiw[q]);
#pragma unroll
        for (int off = 1; off < 64; off <<= 1) mx = max(mx, __shfl_xor(mx, off));

        const int base = (mx >> 20) - 250;
        int idx[8];
#pragma unroll
        for (int q = 0; q < 8; ++q) {
            int t = (hiw[q] >> 20) - base;
            idx[q] = t < 0 ? 0 : t;
        }

        *reinterpret_cast<int4*>(&histc[lane << 2]) = int4{0, 0, 0, 0};
#pragma unroll
        for (int q = 0; q < 8; ++q) atomicAdd(&histc[idx[q]], 1);

        int4 cc = *reinterpret_cast<int4*>(&histc[lane << 2]);
        int s_local = cc.x + cc.y + cc.z + cc.w;

        int s = s_local;
#pragma unroll
        for (int off = 1; off < 64; off <<= 1) {
            int t = __shfl_down(s, off);
            if (lane + off < 64) s += t;
        }
        const int S_gt = s - s_local;
        const int A3 = S_gt;
        const int A2 = A3 + cc.w;
        const int A1 = A2 + cc.z;
        const int A0 = A1 + cc.y;

        int foundB = -1, foundR = 0;
        if (A0 < KSEL && A0 + cc.x >= KSEL) { foundB = (lane << 2) | 0; foundR = KSEL - A0; }
        if (A1 < KSEL && A1 + cc.y >= KSEL) { foundB = (lane << 2) | 1; foundR = KSEL - A1; }
        if (A2 < KSEL && A2 + cc.z >= KSEL) { foundB = (lane << 2) | 2; foundR = KSEL - A2; }
        if (A3 < KSEL && A3 + cc.w >= KSEL) { foundB = (lane << 2) | 3; foundR = KSEL - A3; }

        unsigned long long fm = __ballot(foundB >= 0);
        const int srcB = (int)(__ffsll((unsigned long long)fm) - 1);
        const int B = __shfl(foundB, srcB);
        const int r = __shfl(foundR, srcB);

        unsigned selmask = 0, candmask = 0;
#pragma unroll
        for (int q = 0; q < 8; ++q) {
            if (idx[q] > B) selmask |= (1u << q);
            else if (idx[q] == B) candmask |= (1u << q);
        }

        for (int it = 0; it < r; ++it) {
            float bv = -2.0f; int bq = -1;
#pragma unroll
            for (int q = 0; q < 8; ++q) {
                bool cand = ((candmask >> q) & 1u) != 0;
                if (cand && v[q] > bv) { bv = v[q]; bq = q; }
            }
            int bi = (bq < 0) ? 0x7FFFFFFF : ((bq << 6) | lane);
#pragma unroll
            for (int off = 1; off < 64; off <<= 1) {
                float ov = __shfl_xor(bv, off);
                int   oi = __shfl_xor(bi, off);
                if (ov > bv || (ov == bv && oi < bi)) { bv = ov; bi = oi; }
            }
            if (bi != 0x7FFFFFFF && lane == (bi & 63)) {
                unsigned bit = 1u << (bi >> 6);
                selmask  |= bit;
                candmask &= ~bit;
            }
        }

        // ---- fp64 refinement when the rank-32/33 fp32 gap is too small (reads x from global)
        {
            float vminS = 3.0e38f, vmaxU = -3.0e38f;
#pragma unroll
            for (int q = 0; q < 8; ++q) {
                if ((selmask >> q) & 1u) vminS = fminf(vminS, v[q]);
                else                     vmaxU = fmaxf(vmaxU, v[q]);
            }
#pragma unroll
            for (int off = 1; off < 64; off <<= 1) {
                vminS = fminf(vminS, __shfl_xor(vminS, off));
                vmaxU = fmaxf(vmaxU, __shfl_xor(vmaxU, off));
            }
            const float tau = RTAU * vminS;
            if (vminS - vmaxU < tau) {            // wave-uniform, rare
                const float lo = vmaxU - tau, hi = vminS + tau;
                unsigned candq = 0; int nAbove = 0;
#pragma unroll
                for (int q = 0; q < 8; ++q) {
                    bool inw = (v[q] >= lo) && (v[q] <= hi);
                    if (inw) candq |= (1u << q);
                    if (((selmask >> q) & 1u) && v[q] > hi) ++nAbove;
                }
#pragma unroll
                for (int off = 1; off < 64; off <<= 1) nAbove += __shfl_xor(nAbove, off);
                const int kneed = KSEL - nAbove;
                selmask &= ~candq;                 // drop window members; re-pick in fp64

                const float* xcol = x + ((size_t)(b << 10) << 8) + d0 + c;
                double sV = -1.0; int sSrc = 0; int cnum = 0;
                for (int q = 0; q < 8; ++q) {
                    unsigned long long bal = __ballot((candq >> q) & 1u);
                    while (bal) {
                        int srcl = (int)(__ffsll(bal) - 1);
                        bal &= bal - 1;
                        int m = (q << 6) | srcl;
                        double sr = 0.0, si = 0.0;
                        for (int u = 0; u < 16; ++u) {
                            int n = lane + (u << 6);
                            double xvd = (double)xcol[(size_t)n << 8];
                            int e = (m * n) & 1023;
                            sr = fma(xvd, gwr[e], sr);
                            si = fma(xvd, gwi[e], si);
                        }
#pragma unroll
                        for (int off = 1; off < 64; off <<= 1) {
                            sr += __shfl_xor(sr, off);
                            si += __shfl_xor(si, off);
                        }
                        if (lane == cnum) { sV = sr * sr + si * si; sSrc = (q << 6) | srcl; }
                        ++cnum;
                        if (cnum >= 64) break;
                    }
                    if (cnum >= 64) break;
                }
                for (int it = 0; it < kneed; ++it) {
                    double bv = sV; int bl = lane;
#pragma unroll
                    for (int off = 1; off < 64; off <<= 1) {
                        double ov = __shfl_xor(bv, off);
                        int    ol = __shfl_xor(bl, off);
                        if (ov > bv || (ov == bv && ol < bl)) { bv = ov; bl = ol; }
                    }
                    int wsrc = __shfl(sSrc, bl);
                    if (lane == (wsrc & 63)) selmask |= 1u << (wsrc >> 6);
                    if (lane == bl) sV = -2.0;
                }
            }
        }

        const int cnt = __popc(selmask);
        int pp = cnt;
#pragma unroll
        for (int off = 1; off < 64; off <<= 1) {
            int t = __shfl_up(pp, off);
            if (lane >= off) pp += t;
        }
        int slot = (c << 5) + (pp - cnt);

#pragma unroll
        for (int q = 0; q < 8; ++q) {
            if ((selmask >> q) & 1u) {
                int m = (q << 6) | lane;
                int n = (1024 - m) & 1023;
                float rm = gspR[SPAD(m)], iv = gspI[SPAD(m)];
                float rn = gspR[SPAD(n)], in_ = gspI[SPAD(n)];
                float rr, ii;
                if (c == 0) { rr = 0.5f * (rm + rn);  ii = 0.5f * (iv - in_); }
                else        { rr = 0.5f * (iv + in_); ii = 0.5f * (rn - rm); }
                selMs[slot] = m;
                selAs[slot] = rr * (1.0f / 512.0f);      //  2*Re/T
                selBs[slot] = -ii * (1.0f / 512.0f);     // -2*Im/T
                ++slot;
            }
        }
    }
    __syncthreads();

    // ---- synthesis: thread = (col = tid&1, j = tid>>1 in 0..255); tv = j + 256*i (exact pi/2 steps)
    {
        const int col = tid & 1;
        const int j   = tid >> 1;          // 0..255
        float a0 = 0.f, a1 = 0.f, a2 = 0.f, a3 = 0.f, a4 = 0.f;
        const int cbase = col << 5;
        for (int k = 0; k < KSEL; ++k) {
            const int   m = selMs[cbase + k];
            const float A = selAs[cbase + k];
            const float B = selBs[cbase + k];
            const float th = (float)((m * j) & 1023) * (INV1024 * TWO_PI_F);
            const float cs = __cosf(th);
            const float sn = __sinf(th);
            const float c0 = fmaf(A, cs, B * sn);
            // phase step per i is (pi/2)*(m&3): exact +/-/swap
            switch (m & 3) {
                case 0: a0 += c0; a1 += c0; a2 += c0; a3 += c0; a4 += c0; break;
                case 2: a0 += c0; a1 -= c0; a2 += c0; a3 -= c0; a4 += c0; break;
                case 1: { float c1 = fmaf(B, cs, -(A * sn));
                          a0 += c0; a1 += c1; a2 -= c0; a3 -= c1; a4 += c0; } break;
                default:{ float c1 = fmaf(B, cs, -(A * sn));
                          a0 += c0; a1 -= c1; a2 -= c0; a3 += c1; a4 += c0; } break;
            }
        }
        float* op = out + ((size_t)b * OUT_T + j) * DM + d0 + col;
        op[0]                   = a0;
        op[(size_t)256  * DM]   = a1;
        op[(size_t)512  * DM]   = a2;
        op[(size_t)768  * DM]   = a3;
        op[(size_t)1024 * DM]   = a4;
    }
}

extern "C" void kernel_launch(void* const* d_in, const int* in_sizes, int n_in,
                              void* d_out, int out_size, void* d_ws, size_t ws_size,
                              hipStream_t stream) {
    const float* x = (const float*)d_in[0];
    float* out = (float*)d_out;

    char* w = (char*)d_ws;
    double* gwr  = (double*)(w);
    double* gwi  = (double*)(w + 1024 * sizeof(double));
    float*  gwrF = (float*)(w + 2048 * sizeof(double));
    float*  gwiF = (float*)(w + 2048 * sizeof(double) + 1024 * sizeof(float));

    hipLaunchKernelGGL(fl_twiddle_kernel, dim3(16), dim3(64), 0, stream, gwr, gwi, gwrF, gwiF);
    hipLaunchKernelGGL(fl_fused_kernel, dim3(1024), dim3(512), 0, stream,
                       x, gwr, gwi, gwrF, gwiF, out);
}

// Round 12
// 42.408 us; speedup vs baseline: 1.2931x; 1.1294x over previous
//
#include <hip/hip_runtime.h>
#include <math.h>

#define T_LEN 1024
#define PRED_LEN 256
#define OUT_T (T_LEN + PRED_LEN)
#define DM 256
#define KSEL 32

#define RTAU 1e-4f

// pad every 32 floats by 1 to break power-of-2 bank strides
#define SPAD(i) ((i) + ((i) >> 5))

// W16[e] = exp(-2*pi*i*e/16), fp32
__device__ __constant__ float W16RF[16] = {
    1.0f,  0.92387953f,  0.70710678f,  0.38268343f, 0.0f, -0.38268343f, -0.70710678f, -0.92387953f,
   -1.0f, -0.92387953f, -0.70710678f, -0.38268343f, 0.0f,  0.38268343f,  0.70710678f,  0.92387953f };
__device__ __constant__ float W16IF[16] = {
    0.0f, -0.38268343f, -0.70710678f, -0.92387953f, -1.0f, -0.92387953f, -0.70710678f, -0.38268343f,
    0.0f,  0.38268343f,  0.70710678f,  0.92387953f,  1.0f,  0.92387953f,  0.70710678f,  0.38268343f };

// ---------------- Kernel T: twiddle tables W[e] = exp(-2pi*i*e/1024), fp64 + fp32 ----------------
__global__ void fl_twiddle_kernel(double* __restrict__ gwr, double* __restrict__ gwi,
                                  float* __restrict__ gwrF, float* __restrict__ gwiF) {
    int e = blockIdx.x * 64 + threadIdx.x;
    double ang = (double)e * (6.283185307179586476925286766559 / 1024.0);
    double c = cos(ang), s = -sin(ang);
    gwr[e] = c; gwi[e] = s;
    gwrF[e] = (float)c; gwiF[e] = (float)s;
}

// ---- shared 1024-pt packed FFT core (16x64 four-step), input float2[1024] in LDS ----
// thread (w, lane): outputs ar[q],ai[q] = X[k], k = ((w<<2)|q) + 16*rev6(lane)
__device__ __forceinline__ void fft1024(const float2* __restrict__ xin,
                                        const float* __restrict__ twR,
                                        const float* __restrict__ twI,
                                        int lane, int w, float* ar, float* ai) {
    float Fr[4][4], Fi[4][4];
#pragma unroll
    for (int n1a = 0; n1a < 4; ++n1a) {
        float2 a  = xin[lane + 64 * (n1a + 0)];
        float2 bb = xin[lane + 64 * (n1a + 4)];
        float2 cV = xin[lane + 64 * (n1a + 8)];
        float2 d  = xin[lane + 64 * (n1a + 12)];
        float t0r = a.x + cV.x, t0i = a.y + cV.y;
        float t1r = a.x - cV.x, t1i = a.y - cV.y;
        float t2r = bb.x + d.x, t2i = bb.y + d.y;
        float t3r = bb.x - d.x, t3i = bb.y - d.y;
        Fr[n1a][0] = t0r + t2r;  Fi[n1a][0] = t0i + t2i;
        Fr[n1a][2] = t0r - t2r;  Fi[n1a][2] = t0i - t2i;
        Fr[n1a][1] = t1r + t3i;  Fi[n1a][1] = t1i - t3r;   // t1 - i*t3
        Fr[n1a][3] = t1r - t3i;  Fi[n1a][3] = t1i + t3r;   // t1 + i*t3
    }
#pragma unroll
    for (int q = 0; q < 4; ++q) {
        const int k1 = (w << 2) | q;
        float cr = Fr[0][q], ci = Fi[0][q];
#pragma unroll
        for (int n1a = 1; n1a < 4; ++n1a) {
            int e = (n1a * k1) & 15;
            float wr = W16RF[e], wi = W16IF[e];
            cr += Fr[n1a][q] * wr - Fi[n1a][q] * wi;
            ci += Fr[n1a][q] * wi + Fi[n1a][q] * wr;
        }
        int et = (lane * k1) & 1023;
        float twr = twR[SPAD(et)], twi = twI[SPAD(et)];
        ar[q] = cr * twr - ci * twi;
        ai[q] = cr * twi + ci * twr;
    }
#pragma unroll
    for (int s = 0; s < 6; ++s) {
        const int half = 32 >> s;
        const int e = (lane & (half - 1)) << s;
        const float wr = twR[SPAD(e << 4)];   // W64^e = W1024^(16e)
        const float wi = twI[SPAD(e << 4)];
        const bool up = (lane & half) != 0;
#pragma unroll
        for (int q = 0; q < 4; ++q) {
            float orr = __shfl_xor(ar[q], half);
            float oii = __shfl_xor(ai[q], half);
            float sr = ar[q] + orr, si = ai[q] + oii;
            float dr = orr - ar[q], di = oii - ai[q];
            float ur = dr * wr - di * wi;
            float ui = dr * wi + di * wr;
            ar[q] = up ? ur : sr;
            ai[q] = up ? ui : si;
        }
    }
}

// ---------------- Fused: fp32 FFT + hist top-32 (bitset) + fp64 refine + inverse-FFT synthesis ----------------
// grid = 1024 blocks (one column-pair each), block = 256 threads = 4 waves.
__global__ void __launch_bounds__(256, 4)
fl_fused_kernel(const float* __restrict__ x,
                const double* __restrict__ gwr, const double* __restrict__ gwi,
                const float* __restrict__ gwrF, const float* __restrict__ gwiF,
                float* __restrict__ out) {
    __shared__ float twR[SPAD(1023) + 1], twI[SPAD(1023) + 1];   // fp32 twiddles (persist)
    __shared__ float spR[SPAD(1023) + 1], spI[SPAD(1023) + 1];   // packed spectrum
    __shared__ char smemU[8192];       // union: xsh (FFT1 in) | {mg, hist} | Zc (FFT2 in)
    __shared__ unsigned selw[64];      // selection bitsets: [c][k>>5]
    float2* xsh  = (float2*)smemU;
    float*  mg   = (float*)smemU;                 // [1024]
    int*    hist = (int*)(smemU + 4096);          // [512]

    const int tid  = threadIdx.x;
    const int lane = tid & 63;       // = n2
    const int w    = tid >> 6;       // wave 0..3

    const int bid = blockIdx.x;
    const int sp  = ((bid & 7) << 7) | (bid >> 3);   // XCD-chunked, bijective over 1024
    const int b   = sp >> 7;
    const int d0  = (sp & 127) << 1;

    // stage fp32 twiddles (padded) and the packed column-pair into LDS
    for (int j = 0; j < 4; ++j) {
        int e = tid + (j << 8);
        twR[SPAD(e)] = gwrF[e];
        twI[SPAD(e)] = gwiF[e];
        xsh[e] = *reinterpret_cast<const float2*>(&x[(((size_t)(b << 10) + e) << 8) + d0]);
    }
    if (tid < 64) selw[tid] = 0u;
    __syncthreads();

    // ---- FFT 1: forward transform of packed pair
    float ar[4], ai[4];
    fft1024(xsh, twR, twI, lane, w, ar, ai);

    const int krev = (int)(__brev((unsigned)lane) >> 26);  // rev6(lane)
    __syncthreads();                                       // xsh reads done (mg reuse next)
#pragma unroll
    for (int q = 0; q < 4; ++q) {
        int k = ((w << 2) | q) + (krev << 4);
        spR[SPAD(k)] = ar[q];
        spI[SPAD(k)] = ai[q];
    }
    __syncthreads();

    // ---- magnitudes for both packed columns (conjugate-symmetry unpack); overwrites xsh
#pragma unroll
    for (int h = 0; h < 2; ++h) {
        int m = tid + (h << 8);
        int n = (1024 - m) & 1023;
        float rm = spR[SPAD(m)], iv = spI[SPAD(m)];
        float rn = spR[SPAD(n)], in_ = spI[SPAD(n)];
        float rr0 = 0.5f * (rm + rn),  ii0 = 0.5f * (iv - in_);
        float rr1 = 0.5f * (iv + in_), ii1 = 0.5f * (rn - rm);
        mg[m]       = rr0 * rr0 + ii0 * ii0;
        mg[512 + m] = rr1 * rr1 + ii1 * ii1;
    }
    __syncthreads();

    // ---- histogram top-32 (waves 0,1: one wave per column) + fp64 boundary refinement
    if (tid < 128) {
        const int c = tid >> 6;
        const float* mgc = mg + (c << 9);
        int* histc = hist + (c << 8);

        float v[8]; int hiw[8];
#pragma unroll
        for (int q = 0; q < 8; ++q) v[q] = mgc[(q << 6) | lane];
        if (lane == 0) v[0] = -1.0f;   // exclude m=0; m=512 excluded by range
#pragma unroll
        for (int q = 0; q < 8; ++q) hiw[q] = __float_as_int(v[q]);

        int mx = hiw[0];
#pragma unroll
        for (int q = 1; q < 8; ++q) mx = max(mx, hiw[q]);
#pragma unroll
        for (int off = 1; off < 64; off <<= 1) mx = max(mx, __shfl_xor(mx, off));

        const int base = (mx >> 20) - 250;
        int idx[8];
#pragma unroll
        for (int q = 0; q < 8; ++q) {
            int t = (hiw[q] >> 20) - base;
            idx[q] = t < 0 ? 0 : t;
        }

        *reinterpret_cast<int4*>(&histc[lane << 2]) = int4{0, 0, 0, 0};
#pragma unroll
        for (int q = 0; q < 8; ++q) atomicAdd(&histc[idx[q]], 1);

        int4 cc = *reinterpret_cast<int4*>(&histc[lane << 2]);
        int s_local = cc.x + cc.y + cc.z + cc.w;

        int s = s_local;
#pragma unroll
        for (int off = 1; off < 64; off <<= 1) {
            int t = __shfl_down(s, off);
            if (lane + off < 64) s += t;
        }
        const int S_gt = s - s_local;
        const int A3 = S_gt;
        const int A2 = A3 + cc.w;
        const int A1 = A2 + cc.z;
        const int A0 = A1 + cc.y;

        int foundB = -1, foundR = 0;
        if (A0 < KSEL && A0 + cc.x >= KSEL) { foundB = (lane << 2) | 0; foundR = KSEL - A0; }
        if (A1 < KSEL && A1 + cc.y >= KSEL) { foundB = (lane << 2) | 1; foundR = KSEL - A1; }
        if (A2 < KSEL && A2 + cc.z >= KSEL) { foundB = (lane << 2) | 2; foundR = KSEL - A2; }
        if (A3 < KSEL && A3 + cc.w >= KSEL) { foundB = (lane << 2) | 3; foundR = KSEL - A3; }

        unsigned long long fm = __ballot(foundB >= 0);
        const int srcB = (int)(__ffsll((unsigned long long)fm) - 1);
        const int B = __shfl(foundB, srcB);
        const int r = __shfl(foundR, srcB);

        unsigned selmask = 0, candmask = 0;
#pragma unroll
        for (int q = 0; q < 8; ++q) {
            if (idx[q] > B) selmask |= (1u << q);
            else if (idx[q] == B) candmask |= (1u << q);
        }

        for (int it = 0; it < r; ++it) {
            float bv = -2.0f; int bq = -1;
#pragma unroll
            for (int q = 0; q < 8; ++q) {
                bool cand = ((candmask >> q) & 1u) != 0;
                if (cand && v[q] > bv) { bv = v[q]; bq = q; }
            }
            int bi = (bq < 0) ? 0x7FFFFFFF : ((bq << 6) | lane);
#pragma unroll
            for (int off = 1; off < 64; off <<= 1) {
                float ov = __shfl_xor(bv, off);
                int   oi = __shfl_xor(bi, off);
                if (ov > bv || (ov == bv && oi < bi)) { bv = ov; bi = oi; }
            }
            if (bi != 0x7FFFFFFF && lane == (bi & 63)) {
                unsigned bit = 1u << (bi >> 6);
                selmask  |= bit;
                candmask &= ~bit;
            }
        }

        // ---- fp64 refinement when the rank-32/33 fp32 gap is too small (reads x from global)
        {
            float vminS = 3.0e38f, vmaxU = -3.0e38f;
#pragma unroll
            for (int q = 0; q < 8; ++q) {
                if ((selmask >> q) & 1u) vminS = fminf(vminS, v[q]);
                else                     vmaxU = fmaxf(vmaxU, v[q]);
            }
#pragma unroll
            for (int off = 1; off < 64; off <<= 1) {
                vminS = fminf(vminS, __shfl_xor(vminS, off));
                vmaxU = fmaxf(vmaxU, __shfl_xor(vmaxU, off));
            }
            const float tau = RTAU * vminS;
            if (vminS - vmaxU < tau) {            // wave-uniform, rare
                const float lo = vmaxU - tau, hi = vminS + tau;
                unsigned candq = 0; int nAbove = 0;
#pragma unroll
                for (int q = 0; q < 8; ++q) {
                    bool inw = (v[q] >= lo) && (v[q] <= hi);
                    if (inw) candq |= (1u << q);
                    if (((selmask >> q) & 1u) && v[q] > hi) ++nAbove;
                }
#pragma unroll
                for (int off = 1; off < 64; off <<= 1) nAbove += __shfl_xor(nAbove, off);
                const int kneed = KSEL - nAbove;
                selmask &= ~candq;                 // drop window members; re-pick in fp64

                const float* xcol = x + ((size_t)(b << 10) << 8) + d0 + c;
                double sV = -1.0; int sSrc = 0; int cnum = 0;
                for (int q = 0; q < 8; ++q) {
                    unsigned long long bal = __ballot((candq >> q) & 1u);
                    while (bal) {
                        int srcl = (int)(__ffsll(bal) - 1);
                        bal &= bal - 1;
                        int m = (q << 6) | srcl;
                        double sr = 0.0, si = 0.0;
                        for (int u = 0; u < 16; ++u) {
                            int n = lane + (u << 6);
                            double xvd = (double)xcol[(size_t)n << 8];
                            int e = (m * n) & 1023;
                            sr = fma(xvd, gwr[e], sr);
                            si = fma(xvd, gwi[e], si);
                        }
#pragma unroll
                        for (int off = 1; off < 64; off <<= 1) {
                            sr += __shfl_xor(sr, off);
                            si += __shfl_xor(si, off);
                        }
                        if (lane == cnum) { sV = sr * sr + si * si; sSrc = (q << 6) | srcl; }
                        ++cnum;
                        if (cnum >= 64) break;
                    }
                    if (cnum >= 64) break;
                }
                for (int it = 0; it < kneed; ++it) {
                    double bv = sV; int bl = lane;
#pragma unroll
                    for (int off = 1; off < 64; off <<= 1) {
                        double ov = __shfl_xor(bv, off);
                        int    ol = __shfl_xor(bl, off);
                        if (ov > bv || (ov == bv && ol < bl)) { bv = ov; bl = ol; }
                    }
                    int wsrc = __shfl(sSrc, bl);
                    if (lane == (wsrc & 63)) selmask |= 1u << (wsrc >> 6);
                    if (lane == bl) sV = -2.0;
                }
            }
        }

        // ---- write selection bits (m and its conjugate mirror 1024-m)
#pragma unroll
        for (int q = 0; q < 8; ++q) {
            if ((selmask >> q) & 1u) {
                int m  = (q << 6) | lane;          // 1..511
                int mm = 1024 - m;                 // 513..1023
                atomicOr(&selw[(c << 5) | (m  >> 5)], 1u << (m  & 31));
                atomicOr(&selw[(c << 5) | (mm >> 5)], 1u << (mm & 31));
            }
        }
    }
    __syncthreads();

    // ---- build conj(Z) into smemU: Z[k] = s0*X0[k] + i*s1*X1[k]; Zc = (Z.r, -Z.i)
    {
        float2* zc = (float2*)smemU;
#pragma unroll
        for (int jj = 0; jj < 4; ++jj) {
            int k = tid + (jj << 8);
            int n = (1024 - k) & 1023;
            float Pkr = spR[SPAD(k)], Pki = spI[SPAD(k)];
            float Pnr = spR[SPAD(n)], Pni = spI[SPAD(n)];
            float X0r = 0.5f * (Pkr + Pnr), X0i = 0.5f * (Pki - Pni);
            float X1r = 0.5f * (Pki + Pni), X1i = 0.5f * (Pnr - Pkr);
            bool s0 = (selw[(k >> 5)]      >> (k & 31)) & 1u;
            bool s1 = (selw[32 + (k >> 5)] >> (k & 31)) & 1u;
            float Zr = (s0 ? X0r : 0.0f) - (s1 ? X1i : 0.0f);
            float Zi = (s0 ? X0i : 0.0f) + (s1 ? X1r : 0.0f);
            zc[k] = float2{ Zr, -Zi };
        }
    }
    __syncthreads();

    // ---- FFT 2 (inverse via conjugation): R[t] = DFT(conj(Z))[t] = conj(1024*y[t])
    fft1024(xsh, twR, twI, lane, w, ar, ai);

    // ---- write y: out0 = Re(R)/1024, out1 = -Im(R)/1024; duplicate t<256 to t+1024
    {
        const float S = 1.0f / 1024.0f;
        float2* o2 = reinterpret_cast<float2*>(out + (size_t)b * OUT_T * DM + d0);
#pragma unroll
        for (int q = 0; q < 4; ++q) {
            int t = ((w << 2) | q) + (krev << 4);
            float2 o{ ar[q] * S, -ai[q] * S };
            o2[(size_t)t * 128] = o;
            if (t < PRED_LEN) o2[(size_t)(t + T_LEN) * 128] = o;
        }
    }
}

extern "C" void kernel_launch(void* const* d_in, const int* in_sizes, int n_in,
                              void* d_out, int out_size, void* d_ws, size_t ws_size,
                              hipStream_t stream) {
    const float* x = (const float*)d_in[0];
    float* out = (float*)d_out;

    char* w = (char*)d_ws;
    double* gwr  = (double*)(w);
    double* gwi  = (double*)(w + 1024 * sizeof(double));
    float*  gwrF = (float*)(w + 2048 * sizeof(double));
    float*  gwiF = (float*)(w + 2048 * sizeof(double) + 1024 * sizeof(float));

    hipLaunchKernelGGL(fl_twiddle_kernel, dim3(16), dim3(64), 0, stream, gwr, gwi, gwrF, gwiF);
    hipLaunchKernelGGL(fl_fused_kernel, dim3(1024), dim3(256), 0, stream,
                       x, gwr, gwi, gwrF, gwiF, out);
}